// Round 1
// baseline (27.141 us; speedup 1.0000x reference)
//
#include <hip/hip_runtime.h>

#define N_SRC 16
#define BATCH 8192
#define FEAT 256
#define SLICE_LEN 128

// out[b, n*128 + j] = src[n, b, starts[n] + j]
// One thread per 4 output floats. Output-linear mapping -> coalesced
// reads (contiguous 512B runs per (n,b)) and coalesced float4 stores.
__global__ void FusedSliceCat_kernel(const float* __restrict__ src,
                                     const int* __restrict__ slice_params,
                                     float* __restrict__ out,
                                     int total4) {
    __shared__ int s_start[N_SRC];
    if (threadIdx.x < N_SRC) s_start[threadIdx.x] = slice_params[2 * threadIdx.x];
    __syncthreads();

    int t = blockIdx.x * blockDim.x + threadIdx.x;
    if (t >= total4) return;

    int o   = t << 2;          // output float index (multiple of 4)
    int b   = o >> 11;         // / 2048
    int rem = o & 2047;
    int n   = rem >> 7;        // which source
    int j   = rem & 127;       // position within slice (multiple of 4)

    const float* s = src + (((size_t)n * BATCH + b) * FEAT + s_start[n] + j);
    float4 v;
    v.x = s[0];
    v.y = s[1];
    v.z = s[2];
    v.w = s[3];
    *reinterpret_cast<float4*>(out + o) = v;
}

extern "C" void kernel_launch(void* const* d_in, const int* in_sizes, int n_in,
                              void* d_out, int out_size, void* d_ws, size_t ws_size,
                              hipStream_t stream) {
    const float* src          = (const float*)d_in[0];
    const int*   slice_params = (const int*)d_in[1];
    float*       out          = (float*)d_out;

    const int total  = BATCH * N_SRC * SLICE_LEN;  // 16,777,216 floats
    const int total4 = total / 4;                  // 4,194,304 threads
    const int block  = 256;
    const int grid   = (total4 + block - 1) / block;

    FusedSliceCat_kernel<<<grid, block, 0, stream>>>(src, slice_params, out, total4);
}